// Round 20
// baseline (172.535 us; speedup 1.0000x reference)
//
#include <hip/hip_runtime.h>

#define HH 128
#define WW 224
#define HW_ (HH * WW)   // 28672

typedef short short8 __attribute__((ext_vector_type(8)));
typedef short short4v __attribute__((ext_vector_type(4)));
typedef float f32x4 __attribute__((ext_vector_type(4)));
typedef float float2v __attribute__((ext_vector_type(2)));

__device__ __forceinline__ float lrelu_f(float v) { return v >= 0.f ? v : 0.1f * v; }

__device__ __forceinline__ unsigned short f2bf(float f) {
  union { float f; unsigned u; } x; x.f = f;
  unsigned r = x.u + 0x7fff + ((x.u >> 16) & 1);   // RNE
  return (unsigned short)(r >> 16);
}
__device__ __forceinline__ float bf2f(unsigned short u) {
  union { unsigned u; float f; } x; x.u = ((unsigned)u) << 16; return x.f;
}
__device__ __forceinline__ float asf(unsigned u) {
  union { unsigned u; float f; } x; x.u = u; return x.f;
}

// ---- weight-conversion helpers ----
__device__ __forceinline__ void wfrag_one(const float* __restrict__ w,
                                          unsigned short* __restrict__ wt,
                                          int i, int O, int C, int NFT) {
  const int CB = C / 32;
  const int j = i & 7;
  const int lane = (i >> 3) & 63;
  const int fid = i >> 9;
  const int nfg = fid % NFT;
  const int kcb = fid / NFT;
  const int cb = kcb % CB;
  const int k = kcb / CB;
  const int o = nfg * 16 + (lane & 15);
  const int c = cb * 32 + (lane >> 4) * 8 + j;
  float v = (o < O) ? w[((size_t)o * C + c) * 9 + k] : 0.f;
  wt[i] = f2bf(v);
}
__device__ __forceinline__ void wdcn_one(const float* __restrict__ w,
                                         unsigned short* __restrict__ wt, int i) {
  const int j = i & 7;
  const int lane = (i >> 3) & 63;
  const int fid = i >> 9;
  const int mf = fid & 3;
  const int s = (fid >> 2) % 5;
  const int g = fid / 20;
  const int l15 = lane & 15, lg = lane >> 4;
  const int o = mf * 16 + l15;
  const int t = 2 * s + (lg >> 1);
  const int c = g * 16 + (lg & 1) * 8 + j;
  float v = (t < 9) ? w[((size_t)o * 64 + c) * 9 + t] : 0.f;
  wt[i] = f2bf(v);
}

// ---- prep: blocks [0,1792) transpose inputs -> xnb + xref; [1792,2708) weights ----
__global__ __launch_bounds__(256)
void prep_all(const float* __restrict__ nbr, const float* __restrict__ ref,
              const float* __restrict__ w1, const float* __restrict__ wm1,
              const float* __restrict__ wm2, const float* __restrict__ wm3,
              const float* __restrict__ wdcn,
              unsigned short* __restrict__ xnb, unsigned short* __restrict__ xref,
              unsigned short* __restrict__ wf1, unsigned short* __restrict__ wfm1,
              unsigned short* __restrict__ wfm2, unsigned short* __restrict__ wfm3,
              unsigned short* __restrict__ wdf) {
  __shared__ __align__(16) char ls[64 * 256];   // 16 KB
  if (blockIdx.x >= 1792) {
    int i = (blockIdx.x - 1792) * 256 + threadIdx.x;
    if (i < 73728) { wfrag_one(w1, wf1, i, 64, 128, 4); return; }
    i -= 73728;
    if (i < 36864) { wfrag_one(wm1, wfm1, i, 64, 64, 4); return; }
    i -= 36864;
    if (i < 36864) { wfrag_one(wm2, wfm2, i, 64, 64, 4); return; }
    i -= 36864;
    if (i < 46080) { wfrag_one(wm3, wfm3, i, 72, 64, 5); return; }
    i -= 46080;
    if (i < 40960) wdcn_one(wdcn, wdf, i);
    return;
  }
  const int lane = threadIdx.x & 63;
  const int q = threadIdx.x >> 6;
  const int bxp = blockIdx.x % 448;
  const int b = blockIdx.x / 448;
  const int p0 = bxp * 64;
  const int p = p0 + lane;
  const int c0 = q * 32;
  const float* src = (c0 < 64) ? (nbr + ((size_t)b * 64 + c0) * HW_)
                               : (ref + ((size_t)b * 64 + (c0 - 64)) * HW_);
  unsigned short tmp[32];
  #pragma unroll
  for (int i = 0; i < 32; ++i) tmp[i] = f2bf(src[(size_t)i * HW_ + p]);
  #pragma unroll
  for (int j = 0; j < 4; ++j) {
    const int byte = (c0 * 2 + j * 16) ^ ((lane & 7) << 4);
    *(short8*)(ls + lane * 256 + byte) = *(const short8*)(tmp + j * 8);
  }
  __syncthreads();
  const int tid = threadIdx.x;
  unsigned short* dnb = xnb + ((size_t)b * HW_ + p0) * 64;
  unsigned short* drf = xref + ((size_t)b * HW_ + p0) * 64;
  #pragma unroll
  for (int j = 0; j < 2; ++j) {
    const int unit = tid * 2 + j;
    const int px = unit >> 3, ck = unit & 7;
    const short8 v = *(const short8*)(ls + px * 256 + ((ck * 16) ^ ((px & 7) << 4)));
    *(short8*)(dnb + (size_t)px * 64 + ck * 8) = v;
  }
  #pragma unroll
  for (int j = 0; j < 2; ++j) {
    const int unit = tid * 2 + j;
    const int px = unit >> 3, ck = unit & 7;
    const short8 v = *(const short8*)(ls + px * 256 + (((ck + 8) * 16) ^ ((px & 7) << 4)));
    *(short8*)(drf + (size_t)px * 64 + ck * 8) = v;
  }
}

// ---- conv, 8x32 tile (10x34 halo, 43.5 KB). MFMA operands SWAPPED (A=weights,
// B=pixels) so D row = o: each thread holds 4 consecutive o -> 8B packed stores. ----
template<int CINB, int NFT, int CROW, bool LRELU>
__global__ __launch_bounds__(256, 2)
void conv_lds2(const unsigned short* __restrict__ x0, const unsigned short* __restrict__ x1,
               const unsigned short* __restrict__ wfrag,
               const float* __restrict__ bias, unsigned short* __restrict__ out, int coutReal) {
  __shared__ __align__(16) char xs[10 * 34 * 128];   // 43520 B
  const int tid = threadIdx.x;
  const int lane = tid & 63, wv = tid >> 6;
  const int l15 = lane & 15, lg = lane >> 4;
  const int b = blockIdx.y;
  const int ty = (blockIdx.x / 7) * 8, tx = (blockIdx.x % 7) * 32;

  f32x4 acc[4][NFT];
  #pragma unroll
  for (int mf = 0; mf < 4; ++mf)
    #pragma unroll
    for (int nf = 0; nf < NFT; ++nf) acc[mf][nf] = (f32x4){0.f, 0.f, 0.f, 0.f};

  #pragma unroll 1
  for (int cb2 = 0; cb2 < CINB; ++cb2) {
    if (cb2 > 0) __syncthreads();
    const unsigned short* xb = (cb2 ? x1 : x0) + (size_t)b * HW_ * 64;
    for (int ci = tid; ci < 2720; ci += 256) {
      const int ch = ci & 7;
      const int hp = ci >> 3;
      const int hr = hp / 34, hc = hp % 34;
      const int gy = ty + hr - 1, gx = tx + hc - 1;
      short8 v = (short8)0;
      if (((unsigned)gy < HH) & ((unsigned)gx < WW))
        v = *(const short8*)(xb + (size_t)(gy * WW + gx) * 64 + ch * 8);
      *(short8*)(xs + hp * 128 + ((ch * 16) ^ ((hc & 7) << 4))) = v;
    }
    __syncthreads();

    #pragma unroll
    for (int k = 0; k < 9; ++k) {
      const int ky = k / 3, kx = k % 3;
      #pragma unroll
      for (int cb = 0; cb < 2; ++cb) {
        short8 av[4];
        #pragma unroll
        for (int mf = 0; mf < 4; ++mf) {
          const int hr = 2 * wv + (mf >> 1) + ky;
          const int hc = (mf & 1) * 16 + l15 + kx;
          av[mf] = *(const short8*)(xs + (hr * 34 + hc) * 128
                                    + ((cb * 64 + lg * 16) ^ ((hc & 7) << 4)));
        }
        #pragma unroll
        for (int nf = 0; nf < NFT; ++nf) {
          const short8 bv = *(const short8*)(wfrag
              + ((size_t)((k * (CINB * 2) + cb2 * 2 + cb) * NFT + nf)) * 512 + lane * 8);
          #pragma unroll
          for (int mf = 0; mf < 4; ++mf)
            acc[mf][nf] = __builtin_amdgcn_mfma_f32_16x16x32_bf16(bv, av[mf], acc[mf][nf], 0, 0, 0);
        }
      }
    }
  }

  // epilogue (swapped D): row = o = nf*16 + lg*4 + r, col = pixel (l15)
  unsigned short* ob = out + (size_t)b * HW_ * CROW;
  #pragma unroll
  for (int nf = 0; nf < NFT; ++nf) {
    const int o0 = nf * 16 + lg * 4;
    const f32x4 bz = *(const f32x4*)(bias + o0);   // coutReal==64 here, always valid
    #pragma unroll
    for (int mf = 0; mf < 4; ++mf) {
      const int prow = ty + 2 * wv + (mf >> 1);
      const int pcol = tx + (mf & 1) * 16 + l15;
      unsigned short sv[4];
      #pragma unroll
      for (int r = 0; r < 4; ++r) {
        float vv = acc[mf][nf][r] + bz[r];
        if (LRELU) vv = lrelu_f(vv);
        sv[r] = f2bf(vv);
      }
      *(short4v*)(ob + (size_t)(prow * WW + pcol) * CROW + o0) = *(const short4v*)sv;
    }
  }
}

// ---- conv, 4x32 tile (6x34 halo, 26 KB) — m3 (NFT=5, CROW=72), swapped MFMA ----
template<int NFT, int CROW, bool LRELU>
__global__ __launch_bounds__(256, 2)
void conv_lds(const unsigned short* __restrict__ xt, const unsigned short* __restrict__ wfrag,
              const float* __restrict__ bias, unsigned short* __restrict__ out, int coutReal) {
  __shared__ __align__(16) char xs[6 * 34 * 128];   // 26112 B
  const int tid = threadIdx.x;
  const int lane = tid & 63, wv = tid >> 6;
  const int l15 = lane & 15, lg = lane >> 4;
  const int b = blockIdx.y;
  const int ty = (blockIdx.x / 7) * 4, tx = (blockIdx.x % 7) * 32;
  const unsigned short* xb = xt + (size_t)b * HW_ * 64;

  f32x4 acc[2][NFT];
  #pragma unroll
  for (int mf = 0; mf < 2; ++mf)
    #pragma unroll
    for (int nf = 0; nf < NFT; ++nf) acc[mf][nf] = (f32x4){0.f, 0.f, 0.f, 0.f};

  for (int ci = tid; ci < 1632; ci += 256) {
    const int ch = ci & 7;
    const int hp = ci >> 3;
    const int hr = hp / 34, hc = hp % 34;
    const int gy = ty + hr - 1, gx = tx + hc - 1;
    short8 v = (short8)0;
    if (((unsigned)gy < HH) & ((unsigned)gx < WW))
      v = *(const short8*)(xb + (size_t)(gy * WW + gx) * 64 + ch * 8);
    *(short8*)(xs + hp * 128 + ((ch * 16) ^ ((hc & 7) << 4))) = v;
  }
  __syncthreads();

  #pragma unroll
  for (int k = 0; k < 9; ++k) {
    const int ky = k / 3, kx = k % 3;
    #pragma unroll
    for (int cb = 0; cb < 2; ++cb) {
      short8 av[2];
      #pragma unroll
      for (int mf = 0; mf < 2; ++mf) {
        const int hr = wv + ky;
        const int hc = mf * 16 + l15 + kx;
        av[mf] = *(const short8*)(xs + (hr * 34 + hc) * 128
                                  + ((cb * 64 + lg * 16) ^ ((hc & 7) << 4)));
      }
      #pragma unroll
      for (int nf = 0; nf < NFT; ++nf) {
        const short8 bv = *(const short8*)(wfrag
            + ((size_t)((k * 2 + cb) * NFT + nf)) * 512 + lane * 8);
        #pragma unroll
        for (int mf = 0; mf < 2; ++mf)
          acc[mf][nf] = __builtin_amdgcn_mfma_f32_16x16x32_bf16(bv, av[mf], acc[mf][nf], 0, 0, 0);
      }
    }
  }

  // epilogue (swapped D): row = o = nf*16 + lg*4 + r, col = pixel (l15)
  unsigned short* ob = out + (size_t)b * HW_ * CROW;
  const int prow = ty + wv;
  #pragma unroll
  for (int nf = 0; nf < NFT; ++nf) {
    const int o0 = nf * 16 + lg * 4;
    const bool qv = (o0 < coutReal);   // quads are fully valid or fully invalid (72%4==0)
    f32x4 bz = (f32x4){0.f, 0.f, 0.f, 0.f};
    if (qv) bz = *(const f32x4*)(bias + o0);
    #pragma unroll
    for (int mf = 0; mf < 2; ++mf) {
      const int pcol = tx + mf * 16 + l15;
      unsigned short sv[4];
      #pragma unroll
      for (int r = 0; r < 4; ++r) {
        float vv = acc[mf][nf][r] + bz[r];
        if (LRELU) vv = lrelu_f(vv);
        sv[r] = f2bf(vv);
      }
      if (qv)
        *(short4v*)(ob + (size_t)(prow * WW + pcol) * CROW + o0) = *(const short4v*)sv;
    }
  }
}

// ---- DCN v8: 10x20 halo (25.6 KB -> 6 blocks/CU), boundary-free fast path ----
__global__ __launch_bounds__(256, 2)
void dcn_v8(const unsigned short* __restrict__ xnb,  // [B][HW][64] bf16
            const unsigned short* __restrict__ offt, // [B][HW][72] bf16
            const unsigned short* __restrict__ wdf,  // fragment-ordered [80 fids][512]
            const float* __restrict__ bias, float* __restrict__ out) {
  __shared__ __align__(16) char xs[10 * 20 * 128];   // 25600 B
  const int tid = threadIdx.x;
  const int w = tid >> 6, l = tid & 63;
  const int l15 = l & 15, lg = l >> 4;
  const int b = blockIdx.y;
  const int bx = blockIdx.x;
  const int swz = (bx & 7) * 56 + (bx >> 3);       // bijective: 448 = 8*56
  const int tx = (swz % 14) * 16;
  const int ty = (swz / 14) * 4;
  const int y = ty + w;
  const int x = tx + l15;
  const int p_img = y * WW + x;
  const unsigned short* xb = xnb + (size_t)b * HW_ * 64;

  for (int ci = tid; ci < 1600; ci += 256) {
    const int ch = ci & 7;
    const int pos = ci >> 3;
    const int r = pos / 20, c = pos % 20;
    const int gy = ty - 3 + r, gx = tx - 2 + c;
    short8 v = (short8)0;
    if (((unsigned)gy < HH) & ((unsigned)gx < WW))
      v = *(const short8*)(xb + (size_t)(gy * WW + gx) * 64 + ch * 8);
    *(short8*)(xs + pos * 128 + ((ch * 16) ^ (((r + c) & 7) << 4))) = v;
  }
  __syncthreads();

  const unsigned* od = (const unsigned*)(offt + ((size_t)b * HW_ + p_img) * 72);
  const int thalf = lg >> 1;
  const int cofs0 = (lg & 1) * 8;

  float pyA[5], pxA[5];
  int liveA[5];
  #pragma unroll
  for (int s = 0; s < 5; ++s) {
    const int t = 2 * s + thalf;
    liveA[s] = (t < 9);
    const int tt = liveA[s] ? t : 0;
    pyA[s] = (float)(y - 1 + tt / 3);
    pxA[s] = (float)(x - 1 + tt % 3);
  }

  f32x4 acc[4];
  #pragma unroll
  for (int mf = 0; mf < 4; ++mf) acc[mf] = (f32x4){0.f, 0.f, 0.f, 0.f};

  #pragma unroll 1
  for (int g = 0; g < 4; ++g) {
    const int cofs = g * 16 + cofs0;
    const int chunkB = cofs * 2;
    #pragma unroll
    for (int s = 0; s < 5; ++s) {
      const int live = liveA[s];
      const int t = 2 * s + thalf;
      const unsigned dpair = od[g * 9 + (live ? t : 0)];
      const float dy = bf2f((unsigned short)(dpair & 0xffff));
      const float dx = bf2f((unsigned short)(dpair >> 16));
      const float sy = dy + pyA[s];
      const float sx = dx + pxA[s];
      const float fy = floorf(sy);
      const float fx = floorf(sx);
      const int y0 = (int)fy;
      const int x0 = (int)fx;
      const float ay = sy - fy;
      const float ax = sx - fx;
      const float by = 1.f - ay, bxx = 1.f - ax;
      float w00 = by * bxx, w01 = by * ax, w10 = ay * bxx, w11 = ay * ax;
      const int ry0 = y0 - ty + 3;       // tile-relative, UNCLAMPED
      const int rx0 = x0 - tx + 2;
      const bool inT = (!live) | (((unsigned)ry0 < 9u) & ((unsigned)rx0 < 19u));
      short8 q00, q01, q10, q11;
      if (__all((int)inT)) {
        const int r0 = live ? ry0 : 0;
        const int c0 = live ? rx0 : 0;
        const int b00 = (r0 * 20 + c0) << 7;
        const int sw00 = b00 + (chunkB ^ (((r0 + c0) & 7) << 4));
        const int sw01 = b00 + 128 + (chunkB ^ (((r0 + c0 + 1) & 7) << 4));
        const int b10 = b00 + 2560;
        const int sw10 = b10 + (chunkB ^ (((r0 + c0 + 1) & 7) << 4));
        const int sw11 = b10 + 128 + (chunkB ^ (((r0 + c0 + 2) & 7) << 4));
        q00 = *(const short8*)(xs + sw00);
        q01 = *(const short8*)(xs + sw01);
        q10 = *(const short8*)(xs + sw10);
        q11 = *(const short8*)(xs + sw11);
      } else {
        const bool vy0 = (y0 >= 0) & (y0 < HH);
        const bool vy1 = (y0 + 1 >= 0) & (y0 + 1 < HH);
        const bool vx0 = (x0 >= 0) & (x0 < WW);
        const bool vx1 = (x0 + 1 >= 0) & (x0 + 1 < WW);
        w00 = (vy0 & vx0) ? w00 : 0.f;
        w01 = (vy0 & vx1) ? w01 : 0.f;
        w10 = (vy1 & vx0) ? w10 : 0.f;
        w11 = (vy1 & vx1) ? w11 : 0.f;
        const int cy0 = min(max(y0, 0), HH - 1);
        const int cy1 = min(max(y0 + 1, 0), HH - 1);
        const int cx0 = min(max(x0, 0), WW - 1);
        const int cx1 = min(max(x0 + 1, 0), WW - 1);
        q00 = *(const short8*)(xb + (size_t)(cy0 * WW + cx0) * 64 + cofs);
        q01 = *(const short8*)(xb + (size_t)(cy0 * WW + cx1) * 64 + cofs);
        q10 = *(const short8*)(xb + (size_t)(cy1 * WW + cx0) * 64 + cofs);
        q11 = *(const short8*)(xb + (size_t)(cy1 * WW + cx1) * 64 + cofs);
      }
      short8 pf = (short8)0;
      if (live) {
        const unsigned* u00 = (const unsigned*)&q00;
        const unsigned* u01 = (const unsigned*)&q01;
        const unsigned* u10 = (const unsigned*)&q10;
        const unsigned* u11 = (const unsigned*)&q11;
        unsigned pr[4];
        #pragma unroll
        for (int i = 0; i < 4; ++i) {
          float2v f00, f01, f10, f11;
          f00.x = asf(u00[i] << 16); f00.y = asf(u00[i] & 0xffff0000u);
          f01.x = asf(u01[i] << 16); f01.y = asf(u01[i] & 0xffff0000u);
          f10.x = asf(u10[i] << 16); f10.y = asf(u10[i] & 0xffff0000u);
          f11.x = asf(u11[i] << 16); f11.y = asf(u11[i] & 0xffff0000u);
          const float2v s2 = f00 * w00 + f01 * w01 + f10 * w10 + f11 * w11;
          unsigned pk;
          asm("v_cvt_pk_bf16_f32 %0, %1, %2" : "=v"(pk) : "v"(s2.x), "v"(s2.y));
          pr[i] = pk;
        }
        pf = *(const short8*)pr;
      }
      #pragma unroll
      for (int mf = 0; mf < 4; ++mf) {
        const short8 wf = *(const short8*)(wdf + ((size_t)((g * 5 + s) * 4 + mf)) * 512 + l * 8);
        acc[mf] = __builtin_amdgcn_mfma_f32_16x16x32_bf16(wf, pf, acc[mf], 0, 0, 0);
      }
    }
  }

  float* ob = out + (size_t)b * 64 * HW_;
  #pragma unroll
  for (int mf = 0; mf < 4; ++mf) {
    #pragma unroll
    for (int r = 0; r < 4; ++r) {
      const int o = mf * 16 + lg * 4 + r;
      ob[(size_t)o * HW_ + p_img] = lrelu_f(acc[mf][r] + bias[o]);
    }
  }
}

extern "C" void kernel_launch(void* const* d_in, const int* in_sizes, int n_in,
                              void* d_out, int out_size, void* d_ws, size_t ws_size,
                              hipStream_t stream) {
  const float* nbr   = (const float*)d_in[0];
  const float* ref   = (const float*)d_in[1];
  const float* w_co1 = (const float*)d_in[2];
  const float* b_co1 = (const float*)d_in[3];
  const float* w_m1  = (const float*)d_in[4];
  const float* b_m1  = (const float*)d_in[5];
  const float* w_m2  = (const float*)d_in[6];
  const float* b_m2  = (const float*)d_in[7];
  const float* w_m3  = (const float*)d_in[8];
  const float* b_m3  = (const float*)d_in[9];
  const float* w_dcn = (const float*)d_in[10];
  const float* b_dcn = (const float*)d_in[11];
  float* out = (float*)d_out;

  char* ws = (char*)d_ws;
  unsigned short* xnb   = (unsigned short*)(ws);
  unsigned short* xref  = (unsigned short*)(ws + 14680064);
  unsigned short* offt  = (unsigned short*)(ws + 14680064);   // alias xref (dead by m3)
  unsigned short* featt = (unsigned short*)(ws + 29360128);
  unsigned short* m1t   = (unsigned short*)(ws + 44040192);
  unsigned short* m2t   = (unsigned short*)(ws + 58720256);
  char* wbase = ws + 58720256 + 14680064;                     // 73.40M
  unsigned short* wf1  = (unsigned short*)(wbase);            // 147456
  unsigned short* wfm1 = (unsigned short*)(wbase + 147456);   // 73728
  unsigned short* wfm2 = (unsigned short*)(wbase + 221184);   // 73728
  unsigned short* wfm3 = (unsigned short*)(wbase + 294912);   // 92160
  unsigned short* wdf  = (unsigned short*)(wbase + 387072);   // 81920

  dim3 blk(256);
  prep_all<<<dim3(2708), blk, 0, stream>>>(nbr, ref, w_co1, w_m1, w_m2, w_m3, w_dcn,
                                           xnb, xref, wf1, wfm1, wfm2, wfm3, wdf);

  conv_lds2<2, 4, 64, true ><<<dim3(112, 4), blk, 0, stream>>>(xnb,   xref,  wf1,  b_co1, featt, 64);
  conv_lds2<1, 4, 64, true ><<<dim3(112, 4), blk, 0, stream>>>(featt, featt, wfm1, b_m1,  m1t,   64);
  conv_lds2<1, 4, 64, true ><<<dim3(112, 4), blk, 0, stream>>>(m1t,   m1t,   wfm2, b_m2,  m2t,   64);
  conv_lds <5, 72, false><<<dim3(224, 4), blk, 0, stream>>>(m2t,  wfm3, b_m3,  offt,  72);
  dcn_v8<<<dim3(448, 4), blk, 0, stream>>>(xnb, offt, wdf, b_dcn, out);
}

// Round 21
// 158.533 us; speedup vs baseline: 1.0883x; 1.0883x over previous
//
#include <hip/hip_runtime.h>

#define HH 128
#define WW 224
#define HW_ (HH * WW)   // 28672

typedef short short8 __attribute__((ext_vector_type(8)));
typedef float f32x4 __attribute__((ext_vector_type(4)));
typedef float float2v __attribute__((ext_vector_type(2)));

__device__ __forceinline__ float lrelu_f(float v) { return v >= 0.f ? v : 0.1f * v; }

__device__ __forceinline__ unsigned short f2bf(float f) {
  union { float f; unsigned u; } x; x.f = f;
  unsigned r = x.u + 0x7fff + ((x.u >> 16) & 1);   // RNE
  return (unsigned short)(r >> 16);
}
__device__ __forceinline__ float bf2f(unsigned short u) {
  union { unsigned u; float f; } x; x.u = ((unsigned)u) << 16; return x.f;
}
__device__ __forceinline__ float asf(unsigned u) {
  union { unsigned u; float f; } x; x.u = u; return x.f;
}

// ---- weight-conversion helpers ----
__device__ __forceinline__ void wfrag_one(const float* __restrict__ w,
                                          unsigned short* __restrict__ wt,
                                          int i, int O, int C, int NFT) {
  const int CB = C / 32;
  const int j = i & 7;
  const int lane = (i >> 3) & 63;
  const int fid = i >> 9;
  const int nfg = fid % NFT;
  const int kcb = fid / NFT;
  const int cb = kcb % CB;
  const int k = kcb / CB;
  const int o = nfg * 16 + (lane & 15);
  const int c = cb * 32 + (lane >> 4) * 8 + j;
  float v = (o < O) ? w[((size_t)o * C + c) * 9 + k] : 0.f;
  wt[i] = f2bf(v);
}
__device__ __forceinline__ void wdcn_one(const float* __restrict__ w,
                                         unsigned short* __restrict__ wt, int i) {
  const int j = i & 7;
  const int lane = (i >> 3) & 63;
  const int fid = i >> 9;
  const int mf = fid & 3;
  const int s = (fid >> 2) % 5;
  const int g = fid / 20;
  const int l15 = lane & 15, lg = lane >> 4;
  const int o = mf * 16 + l15;
  const int t = 2 * s + (lg >> 1);
  const int c = g * 16 + (lg & 1) * 8 + j;
  float v = (t < 9) ? w[((size_t)o * 64 + c) * 9 + t] : 0.f;
  wt[i] = f2bf(v);
}

// ---- prep: blocks [0,1792) transpose inputs -> xnb + xref; [1792,2708) weights ----
__global__ __launch_bounds__(256)
void prep_all(const float* __restrict__ nbr, const float* __restrict__ ref,
              const float* __restrict__ w1, const float* __restrict__ wm1,
              const float* __restrict__ wm2, const float* __restrict__ wm3,
              const float* __restrict__ wdcn,
              unsigned short* __restrict__ xnb, unsigned short* __restrict__ xref,
              unsigned short* __restrict__ wf1, unsigned short* __restrict__ wfm1,
              unsigned short* __restrict__ wfm2, unsigned short* __restrict__ wfm3,
              unsigned short* __restrict__ wdf) {
  __shared__ __align__(16) char ls[64 * 256];   // 16 KB
  if (blockIdx.x >= 1792) {
    int i = (blockIdx.x - 1792) * 256 + threadIdx.x;
    if (i < 73728) { wfrag_one(w1, wf1, i, 64, 128, 4); return; }
    i -= 73728;
    if (i < 36864) { wfrag_one(wm1, wfm1, i, 64, 64, 4); return; }
    i -= 36864;
    if (i < 36864) { wfrag_one(wm2, wfm2, i, 64, 64, 4); return; }
    i -= 36864;
    if (i < 46080) { wfrag_one(wm3, wfm3, i, 72, 64, 5); return; }
    i -= 46080;
    if (i < 40960) wdcn_one(wdcn, wdf, i);
    return;
  }
  const int lane = threadIdx.x & 63;
  const int q = threadIdx.x >> 6;
  const int bxp = blockIdx.x % 448;
  const int b = blockIdx.x / 448;
  const int p0 = bxp * 64;
  const int p = p0 + lane;
  const int c0 = q * 32;
  const float* src = (c0 < 64) ? (nbr + ((size_t)b * 64 + c0) * HW_)
                               : (ref + ((size_t)b * 64 + (c0 - 64)) * HW_);
  unsigned short tmp[32];
  #pragma unroll
  for (int i = 0; i < 32; ++i) tmp[i] = f2bf(src[(size_t)i * HW_ + p]);
  #pragma unroll
  for (int j = 0; j < 4; ++j) {
    const int byte = (c0 * 2 + j * 16) ^ ((lane & 7) << 4);
    *(short8*)(ls + lane * 256 + byte) = *(const short8*)(tmp + j * 8);
  }
  __syncthreads();
  const int tid = threadIdx.x;
  unsigned short* dnb = xnb + ((size_t)b * HW_ + p0) * 64;
  unsigned short* drf = xref + ((size_t)b * HW_ + p0) * 64;
  #pragma unroll
  for (int j = 0; j < 2; ++j) {
    const int unit = tid * 2 + j;          // 0..511
    const int px = unit >> 3, ck = unit & 7;
    const short8 v = *(const short8*)(ls + px * 256 + ((ck * 16) ^ ((px & 7) << 4)));
    *(short8*)(dnb + (size_t)px * 64 + ck * 8) = v;
  }
  #pragma unroll
  for (int j = 0; j < 2; ++j) {
    const int unit = tid * 2 + j;
    const int px = unit >> 3, ck = unit & 7;
    const short8 v = *(const short8*)(ls + px * 256 + (((ck + 8) * 16) ^ ((px & 7) << 4)));
    *(short8*)(drf + (size_t)px * 64 + ck * 8) = v;
  }
}

// ---- conv, 8x32 tile (10x34 halo, 43.5 KB). Two input pointers (64-ch slices). ----
template<int CINB, int NFT, int CROW, bool LRELU>
__global__ __launch_bounds__(256, 2)
void conv_lds2(const unsigned short* __restrict__ x0, const unsigned short* __restrict__ x1,
               const unsigned short* __restrict__ wfrag,
               const float* __restrict__ bias, unsigned short* __restrict__ out, int coutReal) {
  __shared__ __align__(16) char xs[10 * 34 * 128];   // 43520 B
  const int tid = threadIdx.x;
  const int lane = tid & 63, wv = tid >> 6;
  const int l15 = lane & 15, lg = lane >> 4;
  const int b = blockIdx.y;
  const int ty = (blockIdx.x / 7) * 8, tx = (blockIdx.x % 7) * 32;

  f32x4 acc[4][NFT];
  #pragma unroll
  for (int mf = 0; mf < 4; ++mf)
    #pragma unroll
    for (int nf = 0; nf < NFT; ++nf) acc[mf][nf] = (f32x4){0.f, 0.f, 0.f, 0.f};

  #pragma unroll 1
  for (int cb2 = 0; cb2 < CINB; ++cb2) {
    if (cb2 > 0) __syncthreads();
    const unsigned short* xb = (cb2 ? x1 : x0) + (size_t)b * HW_ * 64;
    for (int ci = tid; ci < 2720; ci += 256) {
      const int ch = ci & 7;
      const int hp = ci >> 3;
      const int hr = hp / 34, hc = hp % 34;
      const int gy = ty + hr - 1, gx = tx + hc - 1;
      short8 v = (short8)0;
      if (((unsigned)gy < HH) & ((unsigned)gx < WW))
        v = *(const short8*)(xb + (size_t)(gy * WW + gx) * 64 + ch * 8);
      *(short8*)(xs + hp * 128 + ((ch * 16) ^ ((hc & 7) << 4))) = v;
    }
    __syncthreads();

    #pragma unroll
    for (int k = 0; k < 9; ++k) {
      const int ky = k / 3, kx = k % 3;
      #pragma unroll
      for (int cb = 0; cb < 2; ++cb) {
        short8 av[4];
        #pragma unroll
        for (int mf = 0; mf < 4; ++mf) {
          const int hr = 2 * wv + (mf >> 1) + ky;
          const int hc = (mf & 1) * 16 + l15 + kx;
          av[mf] = *(const short8*)(xs + (hr * 34 + hc) * 128
                                    + ((cb * 64 + lg * 16) ^ ((hc & 7) << 4)));
        }
        #pragma unroll
        for (int nf = 0; nf < NFT; ++nf) {
          const short8 bv = *(const short8*)(wfrag
              + ((size_t)((k * (CINB * 2) + cb2 * 2 + cb) * NFT + nf)) * 512 + lane * 8);
          #pragma unroll
          for (int mf = 0; mf < 4; ++mf)
            acc[mf][nf] = __builtin_amdgcn_mfma_f32_16x16x32_bf16(av[mf], bv, acc[mf][nf], 0, 0, 0);
        }
      }
    }
  }

  unsigned short* ob = out + (size_t)b * HW_ * CROW;
  #pragma unroll
  for (int nf = 0; nf < NFT; ++nf) {
    const int o = nf * 16 + l15;
    const bool ov = (o < coutReal);
    const float bz = ov ? bias[o] : 0.f;
    #pragma unroll
    for (int mf = 0; mf < 4; ++mf) {
      const int rr = ty + 2 * wv + (mf >> 1);
      #pragma unroll
      for (int r = 0; r < 4; ++r) {
        const int cc = tx + (mf & 1) * 16 + lg * 4 + r;
        float vv = acc[mf][nf][r] + bz;
        if (LRELU) vv = lrelu_f(vv);
        if (ov) ob[(size_t)(rr * WW + cc) * CROW + o] = f2bf(vv);
      }
    }
  }
}

// ---- conv, 4x32 tile (6x34 halo, 26 KB) — m3 (NFT=5). ----
template<int NFT, int CROW, bool LRELU>
__global__ __launch_bounds__(256, 2)
void conv_lds(const unsigned short* __restrict__ xt, const unsigned short* __restrict__ wfrag,
              const float* __restrict__ bias, unsigned short* __restrict__ out, int coutReal) {
  __shared__ __align__(16) char xs[6 * 34 * 128];   // 26112 B
  const int tid = threadIdx.x;
  const int lane = tid & 63, wv = tid >> 6;
  const int l15 = lane & 15, lg = lane >> 4;
  const int b = blockIdx.y;
  const int ty = (blockIdx.x / 7) * 4, tx = (blockIdx.x % 7) * 32;
  const unsigned short* xb = xt + (size_t)b * HW_ * 64;

  f32x4 acc[2][NFT];
  #pragma unroll
  for (int mf = 0; mf < 2; ++mf)
    #pragma unroll
    for (int nf = 0; nf < NFT; ++nf) acc[mf][nf] = (f32x4){0.f, 0.f, 0.f, 0.f};

  for (int ci = tid; ci < 1632; ci += 256) {
    const int ch = ci & 7;
    const int hp = ci >> 3;
    const int hr = hp / 34, hc = hp % 34;
    const int gy = ty + hr - 1, gx = tx + hc - 1;
    short8 v = (short8)0;
    if (((unsigned)gy < HH) & ((unsigned)gx < WW))
      v = *(const short8*)(xb + (size_t)(gy * WW + gx) * 64 + ch * 8);
    *(short8*)(xs + hp * 128 + ((ch * 16) ^ ((hc & 7) << 4))) = v;
  }
  __syncthreads();

  #pragma unroll
  for (int k = 0; k < 9; ++k) {
    const int ky = k / 3, kx = k % 3;
    #pragma unroll
    for (int cb = 0; cb < 2; ++cb) {
      short8 av[2];
      #pragma unroll
      for (int mf = 0; mf < 2; ++mf) {
        const int hr = wv + ky;
        const int hc = mf * 16 + l15 + kx;
        av[mf] = *(const short8*)(xs + (hr * 34 + hc) * 128
                                  + ((cb * 64 + lg * 16) ^ ((hc & 7) << 4)));
      }
      #pragma unroll
      for (int nf = 0; nf < NFT; ++nf) {
        const short8 bv = *(const short8*)(wfrag
            + ((size_t)((k * 2 + cb) * NFT + nf)) * 512 + lane * 8);
        #pragma unroll
        for (int mf = 0; mf < 2; ++mf)
          acc[mf][nf] = __builtin_amdgcn_mfma_f32_16x16x32_bf16(av[mf], bv, acc[mf][nf], 0, 0, 0);
      }
    }
  }

  unsigned short* ob = out + (size_t)b * HW_ * CROW;
  const int rr = ty + wv;
  #pragma unroll
  for (int nf = 0; nf < NFT; ++nf) {
    const int o = nf * 16 + l15;
    const bool ov = (o < coutReal);
    const float bz = ov ? bias[o] : 0.f;
    #pragma unroll
    for (int mf = 0; mf < 2; ++mf) {
      #pragma unroll
      for (int r = 0; r < 4; ++r) {
        const int cc = tx + mf * 16 + lg * 4 + r;
        float vv = acc[mf][nf][r] + bz;
        if (LRELU) vv = lrelu_f(vv);
        if (ov) ob[(size_t)(rr * WW + cc) * CROW + o] = f2bf(vv);
      }
    }
  }
}

// ---- DCN v8: 10x20 halo (25.6 KB -> 6 blocks/CU), boundary-free fast path ----
__global__ __launch_bounds__(256, 2)
void dcn_v8(const unsigned short* __restrict__ xnb,  // [B][HW][64] bf16
            const unsigned short* __restrict__ offt, // [B][HW][72] bf16
            const unsigned short* __restrict__ wdf,  // fragment-ordered [80 fids][512]
            const float* __restrict__ bias, float* __restrict__ out) {
  __shared__ __align__(16) char xs[10 * 20 * 128];   // 25600 B
  const int tid = threadIdx.x;
  const int w = tid >> 6, l = tid & 63;
  const int l15 = l & 15, lg = l >> 4;
  const int b = blockIdx.y;
  const int bx = blockIdx.x;
  const int swz = (bx & 7) * 56 + (bx >> 3);       // bijective: 448 = 8*56
  const int tx = (swz % 14) * 16;
  const int ty = (swz / 14) * 4;
  const int y = ty + w;
  const int x = tx + l15;
  const int p_img = y * WW + x;
  const unsigned short* xb = xnb + (size_t)b * HW_ * 64;

  for (int ci = tid; ci < 1600; ci += 256) {
    const int ch = ci & 7;
    const int pos = ci >> 3;
    const int r = pos / 20, c = pos % 20;
    const int gy = ty - 3 + r, gx = tx - 2 + c;
    short8 v = (short8)0;
    if (((unsigned)gy < HH) & ((unsigned)gx < WW))
      v = *(const short8*)(xb + (size_t)(gy * WW + gx) * 64 + ch * 8);
    *(short8*)(xs + pos * 128 + ((ch * 16) ^ (((r + c) & 7) << 4))) = v;
  }
  __syncthreads();

  const unsigned* od = (const unsigned*)(offt + ((size_t)b * HW_ + p_img) * 72);
  const int thalf = lg >> 1;
  const int cofs0 = (lg & 1) * 8;

  float pyA[5], pxA[5];
  int liveA[5];
  #pragma unroll
  for (int s = 0; s < 5; ++s) {
    const int t = 2 * s + thalf;
    liveA[s] = (t < 9);
    const int tt = liveA[s] ? t : 0;
    pyA[s] = (float)(y - 1 + tt / 3);
    pxA[s] = (float)(x - 1 + tt % 3);
  }

  f32x4 acc[4];
  #pragma unroll
  for (int mf = 0; mf < 4; ++mf) acc[mf] = (f32x4){0.f, 0.f, 0.f, 0.f};

  #pragma unroll 1
  for (int g = 0; g < 4; ++g) {
    const int cofs = g * 16 + cofs0;
    const int chunkB = cofs * 2;
    #pragma unroll
    for (int s = 0; s < 5; ++s) {
      const int live = liveA[s];
      const int t = 2 * s + thalf;
      const unsigned dpair = od[g * 9 + (live ? t : 0)];
      const float dy = bf2f((unsigned short)(dpair & 0xffff));
      const float dx = bf2f((unsigned short)(dpair >> 16));
      const float sy = dy + pyA[s];
      const float sx = dx + pxA[s];
      const float fy = floorf(sy);
      const float fx = floorf(sx);
      const int y0 = (int)fy;
      const int x0 = (int)fx;
      const float ay = sy - fy;
      const float ax = sx - fx;
      const float by = 1.f - ay, bxx = 1.f - ax;
      float w00 = by * bxx, w01 = by * ax, w10 = ay * bxx, w11 = ay * ax;
      const int ry0 = y0 - ty + 3;       // tile-relative, UNCLAMPED
      const int rx0 = x0 - tx + 2;
      const bool inT = (!live) | (((unsigned)ry0 < 9u) & ((unsigned)rx0 < 19u));
      short8 q00, q01, q10, q11;
      if (__all((int)inT)) {
        const int r0 = live ? ry0 : 0;
        const int c0 = live ? rx0 : 0;
        const int b00 = (r0 * 20 + c0) << 7;
        const int sw00 = b00 + (chunkB ^ (((r0 + c0) & 7) << 4));
        const int sw01 = b00 + 128 + (chunkB ^ (((r0 + c0 + 1) & 7) << 4));
        const int b10 = b00 + 2560;
        const int sw10 = b10 + (chunkB ^ (((r0 + c0 + 1) & 7) << 4));
        const int sw11 = b10 + 128 + (chunkB ^ (((r0 + c0 + 2) & 7) << 4));
        q00 = *(const short8*)(xs + sw00);
        q01 = *(const short8*)(xs + sw01);
        q10 = *(const short8*)(xs + sw10);
        q11 = *(const short8*)(xs + sw11);
      } else {
        const bool vy0 = (y0 >= 0) & (y0 < HH);
        const bool vy1 = (y0 + 1 >= 0) & (y0 + 1 < HH);
        const bool vx0 = (x0 >= 0) & (x0 < WW);
        const bool vx1 = (x0 + 1 >= 0) & (x0 + 1 < WW);
        w00 = (vy0 & vx0) ? w00 : 0.f;
        w01 = (vy0 & vx1) ? w01 : 0.f;
        w10 = (vy1 & vx0) ? w10 : 0.f;
        w11 = (vy1 & vx1) ? w11 : 0.f;
        const int cy0 = min(max(y0, 0), HH - 1);
        const int cy1 = min(max(y0 + 1, 0), HH - 1);
        const int cx0 = min(max(x0, 0), WW - 1);
        const int cx1 = min(max(x0 + 1, 0), WW - 1);
        q00 = *(const short8*)(xb + (size_t)(cy0 * WW + cx0) * 64 + cofs);
        q01 = *(const short8*)(xb + (size_t)(cy0 * WW + cx1) * 64 + cofs);
        q10 = *(const short8*)(xb + (size_t)(cy1 * WW + cx0) * 64 + cofs);
        q11 = *(const short8*)(xb + (size_t)(cy1 * WW + cx1) * 64 + cofs);
      }
      short8 pf = (short8)0;
      if (live) {
        const unsigned* u00 = (const unsigned*)&q00;
        const unsigned* u01 = (const unsigned*)&q01;
        const unsigned* u10 = (const unsigned*)&q10;
        const unsigned* u11 = (const unsigned*)&q11;
        unsigned pr[4];
        #pragma unroll
        for (int i = 0; i < 4; ++i) {
          float2v f00, f01, f10, f11;
          f00.x = asf(u00[i] << 16); f00.y = asf(u00[i] & 0xffff0000u);
          f01.x = asf(u01[i] << 16); f01.y = asf(u01[i] & 0xffff0000u);
          f10.x = asf(u10[i] << 16); f10.y = asf(u10[i] & 0xffff0000u);
          f11.x = asf(u11[i] << 16); f11.y = asf(u11[i] & 0xffff0000u);
          const float2v s2 = f00 * w00 + f01 * w01 + f10 * w10 + f11 * w11;
          unsigned pk;
          asm("v_cvt_pk_bf16_f32 %0, %1, %2" : "=v"(pk) : "v"(s2.x), "v"(s2.y));
          pr[i] = pk;
        }
        pf = *(const short8*)pr;
      }
      #pragma unroll
      for (int mf = 0; mf < 4; ++mf) {
        const short8 wf = *(const short8*)(wdf + ((size_t)((g * 5 + s) * 4 + mf)) * 512 + l * 8);
        acc[mf] = __builtin_amdgcn_mfma_f32_16x16x32_bf16(wf, pf, acc[mf], 0, 0, 0);
      }
    }
  }

  float* ob = out + (size_t)b * 64 * HW_;
  #pragma unroll
  for (int mf = 0; mf < 4; ++mf) {
    #pragma unroll
    for (int r = 0; r < 4; ++r) {
      const int o = mf * 16 + lg * 4 + r;
      ob[(size_t)o * HW_ + p_img] = lrelu_f(acc[mf][r] + bias[o]);
    }
  }
}

extern "C" void kernel_launch(void* const* d_in, const int* in_sizes, int n_in,
                              void* d_out, int out_size, void* d_ws, size_t ws_size,
                              hipStream_t stream) {
  const float* nbr   = (const float*)d_in[0];
  const float* ref   = (const float*)d_in[1];
  const float* w_co1 = (const float*)d_in[2];
  const float* b_co1 = (const float*)d_in[3];
  const float* w_m1  = (const float*)d_in[4];
  const float* b_m1  = (const float*)d_in[5];
  const float* w_m2  = (const float*)d_in[6];
  const float* b_m2  = (const float*)d_in[7];
  const float* w_m3  = (const float*)d_in[8];
  const float* b_m3  = (const float*)d_in[9];
  const float* w_dcn = (const float*)d_in[10];
  const float* b_dcn = (const float*)d_in[11];
  float* out = (float*)d_out;

  char* ws = (char*)d_ws;
  unsigned short* xnb   = (unsigned short*)(ws);
  unsigned short* xref  = (unsigned short*)(ws + 14680064);
  unsigned short* offt  = (unsigned short*)(ws + 14680064);   // alias xref (dead by m3)
  unsigned short* featt = (unsigned short*)(ws + 29360128);
  unsigned short* m1t   = (unsigned short*)(ws + 44040192);
  unsigned short* m2t   = (unsigned short*)(ws + 58720256);
  char* wbase = ws + 58720256 + 14680064;                     // 73.40M
  unsigned short* wf1  = (unsigned short*)(wbase);            // 147456
  unsigned short* wfm1 = (unsigned short*)(wbase + 147456);   // 73728
  unsigned short* wfm2 = (unsigned short*)(wbase + 221184);   // 73728
  unsigned short* wfm3 = (unsigned short*)(wbase + 294912);   // 92160
  unsigned short* wdf  = (unsigned short*)(wbase + 387072);   // 81920

  dim3 blk(256);
  prep_all<<<dim3(2708), blk, 0, stream>>>(nbr, ref, w_co1, w_m1, w_m2, w_m3, w_dcn,
                                           xnb, xref, wf1, wfm1, wfm2, wfm3, wdf);

  conv_lds2<2, 4, 64, true ><<<dim3(112, 4), blk, 0, stream>>>(xnb,   xref,  wf1,  b_co1, featt, 64);
  conv_lds2<1, 4, 64, true ><<<dim3(112, 4), blk, 0, stream>>>(featt, featt, wfm1, b_m1,  m1t,   64);
  conv_lds2<1, 4, 64, true ><<<dim3(112, 4), blk, 0, stream>>>(m1t,   m1t,   wfm2, b_m2,  m2t,   64);
  conv_lds <5, 72, false><<<dim3(224, 4), blk, 0, stream>>>(m2t,  wfm3, b_m3,  offt,  72);
  dcn_v8<<<dim3(448, 4), blk, 0, stream>>>(xnb, offt, wdf, b_dcn, out);
}

// Round 22
// 146.430 us; speedup vs baseline: 1.1783x; 1.0827x over previous
//
#include <hip/hip_runtime.h>

#define HH 128
#define WW 224
#define HW_ (HH * WW)   // 28672

typedef short short8 __attribute__((ext_vector_type(8)));
typedef float f32x4 __attribute__((ext_vector_type(4)));
typedef float float2v __attribute__((ext_vector_type(2)));

__device__ __forceinline__ float lrelu_f(float v) { return v >= 0.f ? v : 0.1f * v; }

__device__ __forceinline__ unsigned short f2bf(float f) {
  union { float f; unsigned u; } x; x.f = f;
  unsigned r = x.u + 0x7fff + ((x.u >> 16) & 1);   // RNE
  return (unsigned short)(r >> 16);
}
__device__ __forceinline__ float bf2f(unsigned short u) {
  union { unsigned u; float f; } x; x.u = ((unsigned)u) << 16; return x.f;
}
__device__ __forceinline__ float asf(unsigned u) {
  union { unsigned u; float f; } x; x.u = u; return x.f;
}

// ---- weight-conversion helpers ----
__device__ __forceinline__ void wfrag_one(const float* __restrict__ w,
                                          unsigned short* __restrict__ wt,
                                          int i, int O, int C, int NFT) {
  const int CB = C / 32;
  const int j = i & 7;
  const int lane = (i >> 3) & 63;
  const int fid = i >> 9;
  const int nfg = fid % NFT;
  const int kcb = fid / NFT;
  const int cb = kcb % CB;
  const int k = kcb / CB;
  const int o = nfg * 16 + (lane & 15);
  const int c = cb * 32 + (lane >> 4) * 8 + j;
  float v = (o < O) ? w[((size_t)o * C + c) * 9 + k] : 0.f;
  wt[i] = f2bf(v);
}
__device__ __forceinline__ void wdcn_one(const float* __restrict__ w,
                                         unsigned short* __restrict__ wt, int i) {
  const int j = i & 7;
  const int lane = (i >> 3) & 63;
  const int fid = i >> 9;
  const int mf = fid & 3;
  const int s = (fid >> 2) % 5;
  const int g = fid / 20;
  const int l15 = lane & 15, lg = lane >> 4;
  const int o = mf * 16 + l15;
  const int t = 2 * s + (lg >> 1);
  const int c = g * 16 + (lg & 1) * 8 + j;
  float v = (t < 9) ? w[((size_t)o * 64 + c) * 9 + t] : 0.f;
  wt[i] = f2bf(v);
}

// ---- prep: blocks [0,1792) transpose inputs -> xnb + xref; [1792,2708) weights ----
__global__ __launch_bounds__(256)
void prep_all(const float* __restrict__ nbr, const float* __restrict__ ref,
              const float* __restrict__ w1, const float* __restrict__ wm1,
              const float* __restrict__ wm2, const float* __restrict__ wm3,
              const float* __restrict__ wdcn,
              unsigned short* __restrict__ xnb, unsigned short* __restrict__ xref,
              unsigned short* __restrict__ wf1, unsigned short* __restrict__ wfm1,
              unsigned short* __restrict__ wfm2, unsigned short* __restrict__ wfm3,
              unsigned short* __restrict__ wdf) {
  __shared__ __align__(16) char ls[64 * 256];   // 16 KB
  if (blockIdx.x >= 1792) {
    int i = (blockIdx.x - 1792) * 256 + threadIdx.x;
    if (i < 73728) { wfrag_one(w1, wf1, i, 64, 128, 4); return; }
    i -= 73728;
    if (i < 36864) { wfrag_one(wm1, wfm1, i, 64, 64, 4); return; }
    i -= 36864;
    if (i < 36864) { wfrag_one(wm2, wfm2, i, 64, 64, 4); return; }
    i -= 36864;
    if (i < 46080) { wfrag_one(wm3, wfm3, i, 72, 64, 5); return; }
    i -= 46080;
    if (i < 40960) wdcn_one(wdcn, wdf, i);
    return;
  }
  const int lane = threadIdx.x & 63;
  const int q = threadIdx.x >> 6;
  const int bxp = blockIdx.x % 448;
  const int b = blockIdx.x / 448;
  const int p0 = bxp * 64;
  const int p = p0 + lane;
  const int c0 = q * 32;
  const float* src = (c0 < 64) ? (nbr + ((size_t)b * 64 + c0) * HW_)
                               : (ref + ((size_t)b * 64 + (c0 - 64)) * HW_);
  unsigned short tmp[32];
  #pragma unroll
  for (int i = 0; i < 32; ++i) tmp[i] = f2bf(src[(size_t)i * HW_ + p]);
  #pragma unroll
  for (int j = 0; j < 4; ++j) {
    const int byte = (c0 * 2 + j * 16) ^ ((lane & 7) << 4);
    *(short8*)(ls + lane * 256 + byte) = *(const short8*)(tmp + j * 8);
  }
  __syncthreads();
  const int tid = threadIdx.x;
  unsigned short* dnb = xnb + ((size_t)b * HW_ + p0) * 64;
  unsigned short* drf = xref + ((size_t)b * HW_ + p0) * 64;
  #pragma unroll
  for (int j = 0; j < 2; ++j) {
    const int unit = tid * 2 + j;          // 0..511
    const int px = unit >> 3, ck = unit & 7;
    const short8 v = *(const short8*)(ls + px * 256 + ((ck * 16) ^ ((px & 7) << 4)));
    *(short8*)(dnb + (size_t)px * 64 + ck * 8) = v;
  }
  #pragma unroll
  for (int j = 0; j < 2; ++j) {
    const int unit = tid * 2 + j;
    const int px = unit >> 3, ck = unit & 7;
    const short8 v = *(const short8*)(ls + px * 256 + (((ck + 8) * 16) ^ ((px & 7) << 4)));
    *(short8*)(drf + (size_t)px * 64 + ck * 8) = v;
  }
}

// ---- conv, 4x32 tile (6x34 halo, 26.1 KB) at 4 blocks/CU (16 waves/CU). ----
// Wave = 1 row x 32 cols (2 m-frags) x NFT*16 outputs. Two input pointers.
template<int CINB, int NFT, int CROW, bool LRELU>
__global__ __launch_bounds__(256, 4)
void conv4(const unsigned short* __restrict__ x0, const unsigned short* __restrict__ x1,
           const unsigned short* __restrict__ wfrag,
           const float* __restrict__ bias, unsigned short* __restrict__ out, int coutReal) {
  __shared__ __align__(16) char xs[6 * 34 * 128];   // 26112 B
  const int tid = threadIdx.x;
  const int lane = tid & 63, wv = tid >> 6;
  const int l15 = lane & 15, lg = lane >> 4;
  const int b = blockIdx.y;
  const int ty = (blockIdx.x / 7) * 4, tx = (blockIdx.x % 7) * 32;

  f32x4 acc[2][NFT];
  #pragma unroll
  for (int mf = 0; mf < 2; ++mf)
    #pragma unroll
    for (int nf = 0; nf < NFT; ++nf) acc[mf][nf] = (f32x4){0.f, 0.f, 0.f, 0.f};

  #pragma unroll 1
  for (int cb2 = 0; cb2 < CINB; ++cb2) {
    if (cb2 > 0) __syncthreads();
    const unsigned short* xb = (cb2 ? x1 : x0) + (size_t)b * HW_ * 64;
    for (int ci = tid; ci < 1632; ci += 256) {
      const int ch = ci & 7;
      const int hp = ci >> 3;
      const int hr = hp / 34, hc = hp % 34;
      const int gy = ty + hr - 1, gx = tx + hc - 1;
      short8 v = (short8)0;
      if (((unsigned)gy < HH) & ((unsigned)gx < WW))
        v = *(const short8*)(xb + (size_t)(gy * WW + gx) * 64 + ch * 8);
      *(short8*)(xs + hp * 128 + ((ch * 16) ^ ((hc & 7) << 4))) = v;
    }
    __syncthreads();

    #pragma unroll
    for (int k = 0; k < 9; ++k) {
      const int ky = k / 3, kx = k % 3;
      #pragma unroll
      for (int cb = 0; cb < 2; ++cb) {
        short8 av[2];
        #pragma unroll
        for (int mf = 0; mf < 2; ++mf) {
          const int hr = wv + ky;
          const int hc = mf * 16 + l15 + kx;
          av[mf] = *(const short8*)(xs + (hr * 34 + hc) * 128
                                    + ((cb * 64 + lg * 16) ^ ((hc & 7) << 4)));
        }
        #pragma unroll
        for (int nf = 0; nf < NFT; ++nf) {
          const short8 bv = *(const short8*)(wfrag
              + ((size_t)((k * (CINB * 2) + cb2 * 2 + cb) * NFT + nf)) * 512 + lane * 8);
          #pragma unroll
          for (int mf = 0; mf < 2; ++mf)
            acc[mf][nf] = __builtin_amdgcn_mfma_f32_16x16x32_bf16(av[mf], bv, acc[mf][nf], 0, 0, 0);
        }
      }
    }
  }

  unsigned short* ob = out + (size_t)b * HW_ * CROW;
  const int rr = ty + wv;
  #pragma unroll
  for (int nf = 0; nf < NFT; ++nf) {
    const int o = nf * 16 + l15;
    const bool ov = (o < coutReal);
    const float bz = ov ? bias[o] : 0.f;
    #pragma unroll
    for (int mf = 0; mf < 2; ++mf) {
      #pragma unroll
      for (int r = 0; r < 4; ++r) {
        const int cc = tx + mf * 16 + lg * 4 + r;
        float vv = acc[mf][nf][r] + bz;
        if (LRELU) vv = lrelu_f(vv);
        if (ov) ob[(size_t)(rr * WW + cc) * CROW + o] = f2bf(vv);
      }
    }
  }
}

// ---- DCN v8: 10x20 halo (25.6 KB -> 6 blocks/CU), boundary-free fast path ----
__global__ __launch_bounds__(256, 2)
void dcn_v8(const unsigned short* __restrict__ xnb,  // [B][HW][64] bf16
            const unsigned short* __restrict__ offt, // [B][HW][72] bf16
            const unsigned short* __restrict__ wdf,  // fragment-ordered [80 fids][512]
            const float* __restrict__ bias, float* __restrict__ out) {
  __shared__ __align__(16) char xs[10 * 20 * 128];   // 25600 B
  const int tid = threadIdx.x;
  const int w = tid >> 6, l = tid & 63;
  const int l15 = l & 15, lg = l >> 4;
  const int b = blockIdx.y;
  const int bx = blockIdx.x;
  const int swz = (bx & 7) * 56 + (bx >> 3);       // bijective: 448 = 8*56
  const int tx = (swz % 14) * 16;
  const int ty = (swz / 14) * 4;
  const int y = ty + w;
  const int x = tx + l15;
  const int p_img = y * WW + x;
  const unsigned short* xb = xnb + (size_t)b * HW_ * 64;

  for (int ci = tid; ci < 1600; ci += 256) {
    const int ch = ci & 7;
    const int pos = ci >> 3;
    const int r = pos / 20, c = pos % 20;
    const int gy = ty - 3 + r, gx = tx - 2 + c;
    short8 v = (short8)0;
    if (((unsigned)gy < HH) & ((unsigned)gx < WW))
      v = *(const short8*)(xb + (size_t)(gy * WW + gx) * 64 + ch * 8);
    *(short8*)(xs + pos * 128 + ((ch * 16) ^ (((r + c) & 7) << 4))) = v;
  }
  __syncthreads();

  const unsigned* od = (const unsigned*)(offt + ((size_t)b * HW_ + p_img) * 72);
  const int thalf = lg >> 1;
  const int cofs0 = (lg & 1) * 8;

  float pyA[5], pxA[5];
  int liveA[5];
  #pragma unroll
  for (int s = 0; s < 5; ++s) {
    const int t = 2 * s + thalf;
    liveA[s] = (t < 9);
    const int tt = liveA[s] ? t : 0;
    pyA[s] = (float)(y - 1 + tt / 3);
    pxA[s] = (float)(x - 1 + tt % 3);
  }

  f32x4 acc[4];
  #pragma unroll
  for (int mf = 0; mf < 4; ++mf) acc[mf] = (f32x4){0.f, 0.f, 0.f, 0.f};

  #pragma unroll 1
  for (int g = 0; g < 4; ++g) {
    const int cofs = g * 16 + cofs0;
    const int chunkB = cofs * 2;
    #pragma unroll
    for (int s = 0; s < 5; ++s) {
      const int live = liveA[s];
      const int t = 2 * s + thalf;
      const unsigned dpair = od[g * 9 + (live ? t : 0)];
      const float dy = bf2f((unsigned short)(dpair & 0xffff));
      const float dx = bf2f((unsigned short)(dpair >> 16));
      const float sy = dy + pyA[s];
      const float sx = dx + pxA[s];
      const float fy = floorf(sy);
      const float fx = floorf(sx);
      const int y0 = (int)fy;
      const int x0 = (int)fx;
      const float ay = sy - fy;
      const float ax = sx - fx;
      const float by = 1.f - ay, bxx = 1.f - ax;
      float w00 = by * bxx, w01 = by * ax, w10 = ay * bxx, w11 = ay * ax;
      const int ry0 = y0 - ty + 3;       // tile-relative, UNCLAMPED
      const int rx0 = x0 - tx + 2;
      const bool inT = (!live) | (((unsigned)ry0 < 9u) & ((unsigned)rx0 < 19u));
      short8 q00, q01, q10, q11;
      if (__all((int)inT)) {
        const int r0 = live ? ry0 : 0;
        const int c0 = live ? rx0 : 0;
        const int b00 = (r0 * 20 + c0) << 7;
        const int sw00 = b00 + (chunkB ^ (((r0 + c0) & 7) << 4));
        const int sw01 = b00 + 128 + (chunkB ^ (((r0 + c0 + 1) & 7) << 4));
        const int b10 = b00 + 2560;
        const int sw10 = b10 + (chunkB ^ (((r0 + c0 + 1) & 7) << 4));
        const int sw11 = b10 + 128 + (chunkB ^ (((r0 + c0 + 2) & 7) << 4));
        q00 = *(const short8*)(xs + sw00);
        q01 = *(const short8*)(xs + sw01);
        q10 = *(const short8*)(xs + sw10);
        q11 = *(const short8*)(xs + sw11);
      } else {
        const bool vy0 = (y0 >= 0) & (y0 < HH);
        const bool vy1 = (y0 + 1 >= 0) & (y0 + 1 < HH);
        const bool vx0 = (x0 >= 0) & (x0 < WW);
        const bool vx1 = (x0 + 1 >= 0) & (x0 + 1 < WW);
        w00 = (vy0 & vx0) ? w00 : 0.f;
        w01 = (vy0 & vx1) ? w01 : 0.f;
        w10 = (vy1 & vx0) ? w10 : 0.f;
        w11 = (vy1 & vx1) ? w11 : 0.f;
        const int cy0 = min(max(y0, 0), HH - 1);
        const int cy1 = min(max(y0 + 1, 0), HH - 1);
        const int cx0 = min(max(x0, 0), WW - 1);
        const int cx1 = min(max(x0 + 1, 0), WW - 1);
        q00 = *(const short8*)(xb + (size_t)(cy0 * WW + cx0) * 64 + cofs);
        q01 = *(const short8*)(xb + (size_t)(cy0 * WW + cx1) * 64 + cofs);
        q10 = *(const short8*)(xb + (size_t)(cy1 * WW + cx0) * 64 + cofs);
        q11 = *(const short8*)(xb + (size_t)(cy1 * WW + cx1) * 64 + cofs);
      }
      short8 pf = (short8)0;
      if (live) {
        const unsigned* u00 = (const unsigned*)&q00;
        const unsigned* u01 = (const unsigned*)&q01;
        const unsigned* u10 = (const unsigned*)&q10;
        const unsigned* u11 = (const unsigned*)&q11;
        unsigned pr[4];
        #pragma unroll
        for (int i = 0; i < 4; ++i) {
          float2v f00, f01, f10, f11;
          f00.x = asf(u00[i] << 16); f00.y = asf(u00[i] & 0xffff0000u);
          f01.x = asf(u01[i] << 16); f01.y = asf(u01[i] & 0xffff0000u);
          f10.x = asf(u10[i] << 16); f10.y = asf(u10[i] & 0xffff0000u);
          f11.x = asf(u11[i] << 16); f11.y = asf(u11[i] & 0xffff0000u);
          const float2v s2 = f00 * w00 + f01 * w01 + f10 * w10 + f11 * w11;
          unsigned pk;
          asm("v_cvt_pk_bf16_f32 %0, %1, %2" : "=v"(pk) : "v"(s2.x), "v"(s2.y));
          pr[i] = pk;
        }
        pf = *(const short8*)pr;
      }
      #pragma unroll
      for (int mf = 0; mf < 4; ++mf) {
        const short8 wf = *(const short8*)(wdf + ((size_t)((g * 5 + s) * 4 + mf)) * 512 + l * 8);
        acc[mf] = __builtin_amdgcn_mfma_f32_16x16x32_bf16(wf, pf, acc[mf], 0, 0, 0);
      }
    }
  }

  float* ob = out + (size_t)b * 64 * HW_;
  #pragma unroll
  for (int mf = 0; mf < 4; ++mf) {
    #pragma unroll
    for (int r = 0; r < 4; ++r) {
      const int o = mf * 16 + lg * 4 + r;
      ob[(size_t)o * HW_ + p_img] = lrelu_f(acc[mf][r] + bias[o]);
    }
  }
}

extern "C" void kernel_launch(void* const* d_in, const int* in_sizes, int n_in,
                              void* d_out, int out_size, void* d_ws, size_t ws_size,
                              hipStream_t stream) {
  const float* nbr   = (const float*)d_in[0];
  const float* ref   = (const float*)d_in[1];
  const float* w_co1 = (const float*)d_in[2];
  const float* b_co1 = (const float*)d_in[3];
  const float* w_m1  = (const float*)d_in[4];
  const float* b_m1  = (const float*)d_in[5];
  const float* w_m2  = (const float*)d_in[6];
  const float* b_m2  = (const float*)d_in[7];
  const float* w_m3  = (const float*)d_in[8];
  const float* b_m3  = (const float*)d_in[9];
  const float* w_dcn = (const float*)d_in[10];
  const float* b_dcn = (const float*)d_in[11];
  float* out = (float*)d_out;

  char* ws = (char*)d_ws;
  unsigned short* xnb   = (unsigned short*)(ws);
  unsigned short* xref  = (unsigned short*)(ws + 14680064);
  unsigned short* offt  = (unsigned short*)(ws + 14680064);   // alias xref (dead by m3)
  unsigned short* featt = (unsigned short*)(ws + 29360128);
  unsigned short* m1t   = (unsigned short*)(ws + 44040192);
  unsigned short* m2t   = (unsigned short*)(ws + 58720256);
  char* wbase = ws + 58720256 + 14680064;                     // 73.40M
  unsigned short* wf1  = (unsigned short*)(wbase);            // 147456
  unsigned short* wfm1 = (unsigned short*)(wbase + 147456);   // 73728
  unsigned short* wfm2 = (unsigned short*)(wbase + 221184);   // 73728
  unsigned short* wfm3 = (unsigned short*)(wbase + 294912);   // 92160
  unsigned short* wdf  = (unsigned short*)(wbase + 387072);   // 81920

  dim3 blk(256);
  prep_all<<<dim3(2708), blk, 0, stream>>>(nbr, ref, w_co1, w_m1, w_m2, w_m3, w_dcn,
                                           xnb, xref, wf1, wfm1, wfm2, wfm3, wdf);

  conv4<2, 4, 64, true ><<<dim3(224, 4), blk, 0, stream>>>(xnb,   xref,  wf1,  b_co1, featt, 64);
  conv4<1, 4, 64, true ><<<dim3(224, 4), blk, 0, stream>>>(featt, featt, wfm1, b_m1,  m1t,   64);
  conv4<1, 4, 64, true ><<<dim3(224, 4), blk, 0, stream>>>(m1t,   m1t,   wfm2, b_m2,  m2t,   64);
  conv4<1, 5, 72, false><<<dim3(224, 4), blk, 0, stream>>>(m2t,   m2t,   wfm3, b_m3,  offt,  72);
  dcn_v8<<<dim3(448, 4), blk, 0, stream>>>(xnb, offt, wdf, b_dcn, out);
}